// Round 9
// baseline (190.000 us; speedup 1.0000x reference)
//
#include <hip/hip_runtime.h>
#include <hip/hip_bf16.h>
#include <stdint.h>

#define NP 30000
#define BBINS 80
#define INCH 16
#define OUTCH 32
#define KDIM 1280       // BBINS*INCH
#define NDIM 512        // OUTCH*TBINS
#define KSTEPS 40       // KDIM/32
#define NROWS (NP * BBINS)   // 2,400,000

typedef __bf16 bf16x8 __attribute__((ext_vector_type(8)));
typedef __bf16 bf16x4 __attribute__((ext_vector_type(4)));
typedef float f32x4 __attribute__((ext_vector_type(4)));

__device__ __forceinline__ void async_ld16(const void* g, void* l) {
    __builtin_amdgcn_global_load_lds(
        (const __attribute__((address_space(1))) unsigned int*)g,
        (__attribute__((address_space(3))) unsigned int*)l,
        16, 0, 0);
}

// ---------------------------------------------------------------------------
// Prep: PW[kc][n][qs][e] bf16 with chunk-XOR swizzle qs ^ ((n>>1)&3), where
// lw[k][n] = W[(b+5t)%80][c][o], k=b*16+c, n=o*16+t. (unchanged, proven)
// ---------------------------------------------------------------------------
__global__ void prep_weights(const float* __restrict__ w, __bf16* __restrict__ pw) {
    int gid = blockIdx.x * 256 + threadIdx.x;           // 655360 total
    int e  = gid & 7;
    int qs = (gid >> 3) & 3;
    int n  = (gid >> 5) & 511;
    int kc = gid >> 14;                                  // 0..39
    int kp = kc * 32 + ((qs ^ ((n >> 1) & 3)) << 3) + e; // 0..1279
    int b = kp >> 4, c = kp & 15;
    int o = n >> 4,  t = n & 15;
    int bid = (b + 5 * t) % BBINS;
    pw[gid] = (__bf16)w[(bid * INCH + c) * OUTCH + o];
}

// ---------------------------------------------------------------------------
// Gather: FOUR lanes per (patch,bin) row (quad member q loads channels
// [4q,4q+4)). ONE variable changed vs the 188.06us R3 baseline: the three
// x gathers are issued with sc0 (GLC) = L1-BYPASS, straight to L2.
// Theory: gather is L1-line-throughput bound (7.2M random 64B line touches,
// ~28K/CU, ~98% L1 miss -> tag+MSHR+fill serialization ~= the observed
// 57us; latency model predicts only ~12us; R5's instr-count dedup was
// neutral -> not issue-bound). x is L2-resident (1.9MB/XCD); quad lanes
// still coalesce to one 64B L2 request. asm block: all 3 loads together,
// early-clobber dests (no alias with in-flight addr regs), then
// vmcnt(0) + sched_barrier(0) per guide rule #18.
// ---------------------------------------------------------------------------
__global__ __launch_bounds__(256) void gather_h(
    const float* __restrict__ x,
    const int*   __restrict__ cidx,
    const float* __restrict__ cval,
    __bf16* __restrict__ h) {
    const int gid = blockIdx.x * 256 + threadIdx.x;      // 9,600,000 total
    const int r = gid >> 2;                              // row 0..NROWS-1
    const int q = gid & 3;                               // channel quad
    const int r3 = r * 3;
    const int i0 = cidx[r3 + 0], i1 = cidx[r3 + 1], i2 = cidx[r3 + 2];
    const float v0 = cval[r3 + 0], v1 = cval[r3 + 1], v2 = cval[r3 + 2];
    const float* ap = x + (size_t)i0 * 16 + q * 4;
    const float* bp = x + (size_t)i1 * 16 + q * 4;
    const float* cp = x + (size_t)i2 * 16 + q * 4;
    f32x4 a, b, c;
    asm volatile(
        "global_load_dwordx4 %0, %3, off sc0\n\t"
        "global_load_dwordx4 %1, %4, off sc0\n\t"
        "global_load_dwordx4 %2, %5, off sc0"
        : "=&v"(a), "=&v"(b), "=&v"(c)
        : "v"(ap), "v"(bp), "v"(cp));
    asm volatile("s_waitcnt vmcnt(0)" ::: "memory");
    __builtin_amdgcn_sched_barrier(0);
    bf16x4 hv;
    hv[0] = (__bf16)(v0 * a[0] + v1 * b[0] + v2 * c[0]);
    hv[1] = (__bf16)(v0 * a[1] + v1 * b[1] + v2 * c[1]);
    hv[2] = (__bf16)(v0 * a[2] + v1 * b[2] + v2 * c[2]);
    hv[3] = (__bf16)(v0 * a[3] + v1 * b[3] + v2 * c[3]);
    *(bf16x4*)((char*)h + (size_t)gid * 8) = hv;
}

// ---------------------------------------------------------------------------
// GEMM + max-over-t.  VERBATIM R3 (58.3us, MfmaUtil 27.6%, 0 conflicts):
// 128x256 tile, wave grid 2x2, 4x8 mfma_f32_16x16x32_bf16, stage->sync->
// compute->sync, both operands conflict-free swizzled.
// ---------------------------------------------------------------------------
__global__ __launch_bounds__(256, 2) void gemm_max(
    const __bf16* __restrict__ h,
    const __bf16* __restrict__ pw,
    float* __restrict__ out) {

    __shared__ __align__(16) __bf16 Alds[128 * 32];      // 8 KB  (row stride 64 B)
    __shared__ __align__(16) __bf16 Blds[256 * 32];      // 16 KB (n stride 64 B)

    const int bid = blockIdx.x;
    const int m    = (bid >> 4) * 8 + (bid & 7);         // 0..239
    const int ncol = (bid >> 3) & 1;                     // 0/1
    if (m >= 235) return;                                // 10 dead pad blocks
    const int mbase = m * 128;

    const int tid  = threadIdx.x;
    const int lane = tid & 63;
    const int wave = tid >> 6;
    const int wave_mrow = wave >> 1;     // 0..1
    const int wave_ncol = wave & 1;      // 0..1

    const int ml = lane & 15, q = lane >> 4;
    const int f = (ml >> 1) & 3;                         // bank-group swizzle
    int a_off[4], b_off[8];
#pragma unroll
    for (int i = 0; i < 4; ++i)
        a_off[i] = (wave_mrow * 64 + i * 16 + ml) * 64 + ((q ^ f) << 4);
#pragma unroll
    for (int j = 0; j < 8; ++j) {
        int nl = wave_ncol * 128 + j * 16 + ml;
        b_off[j] = nl * 64 + ((q ^ f) << 4);
    }

    f32x4 acc[4][8];
#pragma unroll
    for (int i = 0; i < 4; ++i)
#pragma unroll
        for (int j = 0; j < 8; ++j)
            acc[i][j] = (f32x4){0.f, 0.f, 0.f, 0.f};

    const char* hB  = (const char*)h;
    const char* pwB = (const char*)pw + ncol * 16384 + tid * 16;
    int rg0 = mbase + (tid >> 2);        // rows 0..63 of tile
    int rg1 = rg0 + 64;                  // rows 64..127
    if (rg0 > NP - 1) rg0 = NP - 1;
    if (rg1 > NP - 1) rg1 = NP - 1;
    // pre-swizzled source chunk: LDS slot (tid&3) of row (tid>>2) must hold
    // source chunk (tid&3) ^ ((row>>1)&3) = (tid&3) ^ ((tid>>3)&3)
    const int swz = ((tid & 3) ^ ((tid >> 3) & 3)) * 16;
    const char* aSrc0 = hB + (size_t)rg0 * 2560 + swz;
    const char* aSrc1 = hB + (size_t)rg1 * 2560 + swz;
    char* aDst0 = (char*)Alds + tid * 16;
    char* aDst1 = aDst0 + 4096;
    char* bDst  = (char*)Blds + tid * 16;

    for (int kc = 0; kc < KSTEPS; ++kc) {
        const char* bs = pwB + kc * 32768;
#pragma unroll
        for (int i = 0; i < 4; ++i)
            async_ld16(bs + i * 4096, bDst + i * 4096);
        async_ld16(aSrc0 + kc * 64, aDst0);
        async_ld16(aSrc1 + kc * 64, aDst1);
        __syncthreads();

        bf16x8 af[4], bfr[8];
#pragma unroll
        for (int i = 0; i < 4; ++i)
            af[i] = *(const bf16x8*)((const char*)Alds + a_off[i]);
#pragma unroll
        for (int j = 0; j < 8; ++j)
            bfr[j] = *(const bf16x8*)((const char*)Blds + b_off[j]);
#pragma unroll
        for (int i = 0; i < 4; ++i)
#pragma unroll
            for (int j = 0; j < 8; ++j)
                acc[i][j] = __builtin_amdgcn_mfma_f32_16x16x32_bf16(
                    af[i], bfr[j], acc[i][j], 0, 0, 0);
        __syncthreads();
    }

    const int rgrp = lane >> 4;
    const int tl   = lane & 15;
#pragma unroll
    for (int i = 0; i < 4; ++i) {
#pragma unroll
        for (int j = 0; j < 8; ++j) {
            float v0 = acc[i][j][0], v1 = acc[i][j][1];
            float v2 = acc[i][j][2], v3 = acc[i][j][3];
#pragma unroll
            for (int off = 1; off < 16; off <<= 1) {
                v0 = fmaxf(v0, __shfl_xor(v0, off));
                v1 = fmaxf(v1, __shfl_xor(v1, off));
                v2 = fmaxf(v2, __shfl_xor(v2, off));
                v3 = fmaxf(v3, __shfl_xor(v3, off));
            }
            if (tl == 0) {
                const int o  = ncol * 16 + wave_ncol * 8 + j;
                const int pr = mbase + wave_mrow * 64 + i * 16 + rgrp * 4;
                if (pr + 0 < NP) out[(pr + 0) * 32 + o] = v0;
                if (pr + 1 < NP) out[(pr + 1) * 32 + o] = v1;
                if (pr + 2 < NP) out[(pr + 2) * 32 + o] = v2;
                if (pr + 3 < NP) out[(pr + 3) * 32 + o] = v3;
            }
        }
    }
}

extern "C" void kernel_launch(void* const* d_in, const int* in_sizes, int n_in,
                              void* d_out, int out_size, void* d_ws, size_t ws_size,
                              hipStream_t stream) {
    const float* x    = (const float*)d_in[0];
    const int*   cidx = (const int*)d_in[1];
    const float* cval = (const float*)d_in[2];
    const float* w    = (const float*)d_in[3];
    float* out = (float*)d_out;

    __bf16* pw = (__bf16*)d_ws;                               // 1.31 MB
    __bf16* h  = (__bf16*)((char*)d_ws + (2 << 20));          // 76.8 MB @ +2MB

    hipLaunchKernelGGL(prep_weights, dim3(2560), dim3(256), 0, stream, w, pw);
    hipLaunchKernelGGL(gather_h, dim3(NROWS * 4 / 256), dim3(256), 0, stream,
                       x, cidx, cval, h);
    hipLaunchKernelGGL(gemm_max, dim3(480), dim3(256), 0, stream,
                       h, (const __bf16*)pw, out);
}

// Round 10
// 185.614 us; speedup vs baseline: 1.0236x; 1.0236x over previous
//
#include <hip/hip_runtime.h>
#include <hip/hip_bf16.h>
#include <stdint.h>

#define NP 30000
#define BBINS 80
#define INCH 16
#define OUTCH 32
#define KDIM 1280       // BBINS*INCH
#define NDIM 512        // OUTCH*TBINS
#define KSTEPS 40       // KDIM/32
#define NROWS (NP * BBINS)   // 2,400,000
#define MTILES 235      // ceil(NP/128)

typedef __bf16 bf16x8 __attribute__((ext_vector_type(8)));
typedef __bf16 bf16x4 __attribute__((ext_vector_type(4)));
typedef float f32x4 __attribute__((ext_vector_type(4)));

__device__ __forceinline__ void async_ld16(const void* g, void* l) {
    __builtin_amdgcn_global_load_lds(
        (const __attribute__((address_space(1))) unsigned int*)g,
        (__attribute__((address_space(3))) unsigned int*)l,
        16, 0, 0);
}

// ---------------------------------------------------------------------------
// Prep: COMPACT weights wc[bid][o][c] bf16 (80*32*16 = 80KB). The old 1.31MB
// rotation-expanded pw is gone: the (b+5t)%80 rotation is now realized as
// LDS addressing inside gemm_max. wc[(bid*32+o)*16+c] = w[(bid*16+c)*32+o].
// ---------------------------------------------------------------------------
__global__ void prep_wc(const float* __restrict__ w, __bf16* __restrict__ wc) {
    int gid = blockIdx.x * 256 + threadIdx.x;            // 40960 total
    int c   = gid & 15;
    int o   = (gid >> 4) & 31;
    int bid = gid >> 9;                                  // 0..79
    wc[gid] = (__bf16)w[(bid * INCH + c) * OUTCH + o];
}

// ---------------------------------------------------------------------------
// Gather: verbatim R3 (57.6-60us proven). FOUR lanes per (patch,bin) row;
// quad member q loads channels [4q,4q+4) of the 3 support rows.
// ---------------------------------------------------------------------------
__global__ __launch_bounds__(256) void gather_h(
    const float* __restrict__ x,
    const int*   __restrict__ cidx,
    const float* __restrict__ cval,
    __bf16* __restrict__ h) {
    const int gid = blockIdx.x * 256 + threadIdx.x;      // 9,600,000 total
    const int r = gid >> 2;                              // row 0..NROWS-1
    const int q = gid & 3;                               // channel quad
    const int r3 = r * 3;
    const int i0 = cidx[r3 + 0], i1 = cidx[r3 + 1], i2 = cidx[r3 + 2];
    const float v0 = cval[r3 + 0], v1 = cval[r3 + 1], v2 = cval[r3 + 2];
    const float4 a = *(const float4*)(x + (size_t)i0 * 16 + q * 4);
    const float4 b = *(const float4*)(x + (size_t)i1 * 16 + q * 4);
    const float4 c = *(const float4*)(x + (size_t)i2 * 16 + q * 4);
    bf16x4 hv;
    hv[0] = (__bf16)(v0 * a.x + v1 * b.x + v2 * c.x);
    hv[1] = (__bf16)(v0 * a.y + v1 * b.y + v2 * c.y);
    hv[2] = (__bf16)(v0 * a.z + v1 * b.z + v2 * c.z);
    hv[3] = (__bf16)(v0 * a.w + v1 * b.w + v2 * c.w);
    *(bf16x4*)((char*)h + (size_t)gid * 8) = hv;
}

// ---------------------------------------------------------------------------
// GEMM + max-over-t with LDS-RESIDENT COMPACT B.
// R9 unified theory: gather AND gemm are L2-request-rate bound (~6.5-8.5
// 64B-req/cy/XCD explains all 9 rounds). gemm's 7.2M requests were 4.8M of
// B re-streaming the 16x rotation-EXPANDED pw (640KB x 470 blocks). Fix:
// hold the 80KB compact weights resident in LDS for the whole kernel and
// compute the rotation (b+5t)%80 in the B-fragment ADDRESS:
//   byte = bid*1024 + ((o*2+ch) ^ (bid&7))*16,  bid=(b+5t)%80, ch=(q&1)
// XOR-swizzle (bid&7)<<4: per 16-lane phase, 5t mod 8 covers 8 bank-groups
// twice -> 2-way = free. Fill Wlds via async_ld16 with involution-
// preswizzled SOURCE (dest linear, rule #21).
// Block: 128 rows x FULL N=512, 512 thr (8 waves, 2Mx4N, wave 64x128 =
// proven 4x8 acc). Per k-step stages ONLY A: 1 async_ld16/thread (proven
// pre-swizzled A source + q^f read). gemm requests: 7.2M -> ~1.6M.
// ---------------------------------------------------------------------------
__global__ __launch_bounds__(512, 2) void gemm_max(
    const __bf16* __restrict__ h,
    const __bf16* __restrict__ wc,
    float* __restrict__ out) {

    __shared__ __align__(16) __bf16 Wlds[80 * 32 * 16];  // 80 KB, swizzled
    __shared__ __align__(16) __bf16 Alds[128 * 32];      // 8 KB (row stride 64B)

    const int tid  = threadIdx.x;
    const int lane = tid & 63;
    const int wave = tid >> 6;           // 0..7
    const int wave_mrow = wave >> 2;     // 0..1
    const int wave_ncol = wave & 3;      // 0..3
    const int mbase = blockIdx.x * 128;

    // ---- one-time Wlds fill: 5120 x 16B chunks, 10/thread; linear dest +
    // involution-preswizzled source (XOR preserves bid bits >=10) ----
    {
        const char* src = (const char*)wc;
        char* dst = (char*)Wlds + tid * 16;
#pragma unroll
        for (int i = 0; i < 10; ++i) {
            const int byte = tid * 16 + i * 8192;
            const int bid  = byte >> 10;
            async_ld16(src + (byte ^ ((bid & 7) << 4)), dst + i * 8192);
        }
    }

    const int ml = lane & 15, q = lane >> 4;
    const int f  = (ml >> 1) & 3;
    int a_off[4];
#pragma unroll
    for (int i = 0; i < 4; ++i)
        a_off[i] = (wave_mrow * 64 + i * 16 + ml) * 64 + ((q ^ f) << 4);

    // B address state: vj4[j] = (o*2+ch)<<4 (bits 4-9); per kstep
    // addr_j = bid*1024 + (vj4[j] ^ ((bid&7)<<4)),  bid=(2kc+(q>>1)+5*ml)%80
    const int ch = q & 1;
    int vj4[8];
#pragma unroll
    for (int j = 0; j < 8; ++j) {
        const int o = wave_ncol * 8 + j;
        vj4[j] = (o * 2 + ch) << 4;
    }
    int bid = (q >> 1) + 5 * ml;         // kc=0 (< 80)

    f32x4 acc[4][8];
#pragma unroll
    for (int i = 0; i < 4; ++i)
#pragma unroll
        for (int j = 0; j < 8; ++j)
            acc[i][j] = (f32x4){0.f, 0.f, 0.f, 0.f};

    // A staging: row = tid>>2 (0..127), chunk = tid&3, pre-swizzled source
    int rg = mbase + (tid >> 2);
    if (rg > NP - 1) rg = NP - 1;
    const int swz = ((tid & 3) ^ ((tid >> 3) & 3)) * 16;
    const char* aSrc = (const char*)h + (size_t)rg * 2560 + swz;
    char* aDst = (char*)Alds + tid * 16;

    for (int kc = 0; kc < KSTEPS; ++kc) {
        async_ld16(aSrc + kc * 64, aDst);
        __syncthreads();                 // drains A (and Wlds fill at kc=0)

        bf16x8 af[4], bfr[8];
#pragma unroll
        for (int i = 0; i < 4; ++i)
            af[i] = *(const bf16x8*)((const char*)Alds + a_off[i]);
        const int bidK = bid << 10;
        const int b74  = (bid & 7) << 4;
#pragma unroll
        for (int j = 0; j < 8; ++j)
            bfr[j] = *(const bf16x8*)((const char*)Wlds + (bidK + (vj4[j] ^ b74)));
#pragma unroll
        for (int i = 0; i < 4; ++i)
#pragma unroll
            for (int j = 0; j < 8; ++j)
                acc[i][j] = __builtin_amdgcn_mfma_f32_16x16x32_bf16(
                    af[i], bfr[j], acc[i][j], 0, 0, 0);
        __syncthreads();                 // all waves done with Alds

        bid += 2;
        if (bid >= BBINS) bid -= BBINS;
    }

    const int rgrp = lane >> 4;
    const int tl   = lane & 15;
#pragma unroll
    for (int i = 0; i < 4; ++i) {
#pragma unroll
        for (int j = 0; j < 8; ++j) {
            float v0 = acc[i][j][0], v1 = acc[i][j][1];
            float v2 = acc[i][j][2], v3 = acc[i][j][3];
#pragma unroll
            for (int off = 1; off < 16; off <<= 1) {
                v0 = fmaxf(v0, __shfl_xor(v0, off));
                v1 = fmaxf(v1, __shfl_xor(v1, off));
                v2 = fmaxf(v2, __shfl_xor(v2, off));
                v3 = fmaxf(v3, __shfl_xor(v3, off));
            }
            if (tl == 0) {
                const int o  = wave_ncol * 8 + j;
                const int pr = mbase + wave_mrow * 64 + i * 16 + rgrp * 4;
                if (pr + 0 < NP) out[(pr + 0) * 32 + o] = v0;
                if (pr + 1 < NP) out[(pr + 1) * 32 + o] = v1;
                if (pr + 2 < NP) out[(pr + 2) * 32 + o] = v2;
                if (pr + 3 < NP) out[(pr + 3) * 32 + o] = v3;
            }
        }
    }
}

extern "C" void kernel_launch(void* const* d_in, const int* in_sizes, int n_in,
                              void* d_out, int out_size, void* d_ws, size_t ws_size,
                              hipStream_t stream) {
    const float* x    = (const float*)d_in[0];
    const int*   cidx = (const int*)d_in[1];
    const float* cval = (const float*)d_in[2];
    const float* w    = (const float*)d_in[3];
    float* out = (float*)d_out;

    __bf16* wc = (__bf16*)d_ws;                               // 80 KB compact
    __bf16* h  = (__bf16*)((char*)d_ws + (2 << 20));          // 76.8 MB @ +2MB

    hipLaunchKernelGGL(prep_wc, dim3(160), dim3(256), 0, stream, w, wc);
    hipLaunchKernelGGL(gather_h, dim3(NROWS * 4 / 256), dim3(256), 0, stream,
                       x, cidx, cval, h);
    hipLaunchKernelGGL(gemm_max, dim3(MTILES), dim3(512), 0, stream,
                       h, (const __bf16*)wc, out);
}